// Round 18
// baseline (209.629 us; speedup 1.0000x reference)
//
#include <hip/hip_runtime.h>
#include <hip/hip_bf16.h>
#include <cstdint>
#include <cstddef>

typedef short short8 __attribute__((ext_vector_type(8)));
typedef float floatx4 __attribute__((ext_vector_type(4)));
typedef float floatx16 __attribute__((ext_vector_type(16)));
typedef unsigned short u16;
typedef unsigned int u32;

__device__ __forceinline__ u16 f2bf(float f) {
    __hip_bfloat16 h = __float2bfloat16(f);
    return __builtin_bit_cast(u16, h);
}

__device__ __forceinline__ void gload_lds16(const void* g, void* l) {
    __builtin_amdgcn_global_load_lds(
        (const __attribute__((address_space(1))) void*)g,
        (__attribute__((address_space(3))) void*)l, 16, 0, 0);
}

// ---------------- prep: weight transposes only (x-cvt moved into gemm4 staging) ----
__global__ __launch_bounds__(256) void prep(const float* __restrict__ wq, const float* __restrict__ wkvd,
                                            const float* __restrict__ wkvu, const float* __restrict__ wo,
                                            u16* __restrict__ wql_t, u16* __restrict__ wkvu_t,
                                            u16* __restrict__ wo_t) {
    const int b = blockIdx.x;
    __shared__ float tile[32][33];
    const float* W; u16* Wt; int K, N, lb;
    if (b < 1024)      { W = wq;   Wt = wql_t;                       K = 1024; N = 1024; lb = b; }
    else if (b < 1152) { W = wkvd; Wt = wql_t + (size_t)1024 * 1024; K = 1024; N = 128;  lb = b - 1024; }
    else if (b < 1408) { W = wkvu; Wt = wkvu_t;                      K = 128;  N = 2048; lb = b - 1152; }
    else               { W = wo;   Wt = wo_t;                        K = 1024; N = 1024; lb = b - 1408; }
    const int nb = N / 32;
    const int n0 = (lb % nb) * 32, k0 = (lb / nb) * 32;
    const int tx = threadIdx.x & 31, ty = threadIdx.x >> 5;
    #pragma unroll
    for (int i = 0; i < 32; i += 8)
        tile[ty + i][tx] = W[(size_t)(k0 + ty + i) * N + n0 + tx];
    __syncthreads();
    #pragma unroll
    for (int i = 0; i < 32; i += 8)
        Wt[(size_t)(n0 + ty + i) * K + k0 + tx] = f2bf(tile[tx][ty + i]);
}

// ---------------- 128x128 BK=64 bf16 GEMM: C = A[M][K] * Bt[N][K]^T ----------------
// r13-proven core (gemm 52/52 us, MfmaUtil ~30%, 0 bank conflicts, VGPR 64):
// 16x16x32 MFMA, 2-phase m97-class, 256 threads / 4 waves (2x2), wave tile 64x64,
// single 32KB LDS/operand, chunk-XOR involution, launch_bounds(256,4).
// MODE 4 delta (r17): A is the raw f32 x — reg-staged (8 coalesced float4 loads),
// f2bf-converted, ds_write_b64 into the SAME swizzled layout (per-lane write addr
// carries the involution; 16 lanes span one 128B row-block = conflict-free).
// Kills prep's 96MB x-cvt pass; A-fetch doubles (hidden, kernel is 17.7% HBM).
// DO NOT RE-TRY (measured regressions): 32x32x16 frags (4.7M conflicts, r14);
// launch_bounds(256,5) (VGPR cap 48 -> acc spill, FETCH 4.5x, r15).
template <int MODE>
__global__ __launch_bounds__(256, 4) void gemm_bt64(const void* __restrict__ Ain, const u16* __restrict__ Bt,
                                                    void* __restrict__ C, int M, int N, int K, int ncols) {
    __shared__ __align__(16) u16 As[128 * 64];
    __shared__ __align__(16) u16 Bs[128 * 64];
    const int tid = threadIdx.x;
    const int lane = tid & 63, wid = tid >> 6;
    const int wr = wid >> 1, wc = wid & 1;
    const int l15 = lane & 15, hi = lane >> 4;

    const int nwg = gridDim.x, q8 = nwg >> 3;
    const int wg = (blockIdx.x & 7) * q8 + (blockIdx.x >> 3);
    const int m0 = (wg / ncols) * 128, n0 = (wg % ncols) * 128;

    const u16* Ab = (MODE == 4) ? nullptr : (const u16*)Ain + (size_t)m0 * K;
    const float* Af = (MODE == 4) ? (const float*)Ain + (size_t)m0 * K : nullptr;
    const u16* Bb = Bt + (size_t)n0 * K;

    u32 soff[4];
    #pragma unroll
    for (int l = 0; l < 4; l++) {
        int p = l * 256 + tid, c = p ^ ((p >> 3) & 7);
        soff[l] = (u32)((c >> 3) * K + (c & 7) * 8);
    }

    // MODE4: f32-quad staging offsets. quad fq = l*256+tid -> row r=fq>>4, q=fq&15;
    // bf16 chunk c = r*8 + (q>>1), half = q&1; LDS u16 off = pos(c)*8 + half*4.
    u32 foff[8];
    int loffA[8];
    if (MODE == 4) {
        #pragma unroll
        for (int l = 0; l < 8; l++) {
            int fq = l * 256 + tid;
            int r = fq >> 4, q = fq & 15;
            foff[l] = (u32)(r * K + q * 4);
            int c = r * 8 + (q >> 1);
            loffA[l] = ((c ^ ((c >> 3) & 7)) << 3) + ((q & 1) << 2);
        }
    }

    int afo[4][2], bfo[4][2];
    #pragma unroll
    for (int i = 0; i < 4; i++) {
        #pragma unroll
        for (int ks = 0; ks < 2; ks++) {
            int ra = wr * 64 + i * 16 + l15;
            afo[i][ks] = ((ra * 8 + ks * 4 + hi) ^ (ra & 7)) * 8;
            int rb = wc * 64 + i * 16 + l15;
            bfo[i][ks] = ((rb * 8 + ks * 4 + hi) ^ (rb & 7)) * 8;
        }
    }

    floatx4 acc[4][4] = {};

    for (int k0 = 0; k0 < K; k0 += 64) {
        #pragma unroll
        for (int l = 0; l < 4; l++)
            gload_lds16(Bb + soff[l] + k0, Bs + (size_t)(l * 256 + wid * 64) * 8);
        if (MODE == 4) {
            // A: f32 reg-stage + cvt + swizzled ds_write (2 rounds of 4 to cap VGPRs)
            #pragma unroll
            for (int rnd = 0; rnd < 2; rnd++) {
                float4 t[4];
                #pragma unroll
                for (int l = 0; l < 4; l++)
                    t[l] = *(const float4*)&Af[foff[rnd * 4 + l] + k0];
                #pragma unroll
                for (int l = 0; l < 4; l++) {
                    ushort4 o;
                    o.x = f2bf(t[l].x); o.y = f2bf(t[l].y);
                    o.z = f2bf(t[l].z); o.w = f2bf(t[l].w);
                    *(ushort4*)&As[loffA[rnd * 4 + l]] = o;
                }
            }
        } else {
            #pragma unroll
            for (int l = 0; l < 4; l++)
                gload_lds16(Ab + soff[l] + k0, As + (size_t)(l * 256 + wid * 64) * 8);
        }
        __syncthreads();
        #pragma unroll
        for (int ks = 0; ks < 2; ks++) {
            short8 af[4], bf[4];
            #pragma unroll
            for (int i = 0; i < 4; i++) af[i] = *(const short8*)&As[afo[i][ks]];
            #pragma unroll
            for (int j = 0; j < 4; j++) bf[j] = *(const short8*)&Bs[bfo[j][ks]];
            #pragma unroll
            for (int i = 0; i < 4; i++) {
                #pragma unroll
                for (int j = 0; j < 4; j++)
                    acc[i][j] = __builtin_amdgcn_mfma_f32_16x16x32_bf16(af[i], bf[j], acc[i][j], 0, 0, 0);
            }
        }
        __syncthreads();
    }

    const int cr = hi * 4, cc = l15;
    #pragma unroll
    for (int i = 0; i < 4; i++) {
        #pragma unroll
        for (int j = 0; j < 4; j++) {
            int row = m0 + wr * 64 + i * 16 + cr;
            int col = n0 + wc * 64 + j * 16 + cc;
            #pragma unroll
            for (int r = 0; r < 4; r++) {
                float v = acc[i][j][r];
                int rr = row + r;
                if (MODE == 0) {
                    ((float*)C)[(size_t)rr * N + col] = v;
                } else {  // MODE 4
                    if (col < 1024) {
                        int h = col >> 6, dd = col & 63;
                        ((u16*)C)[(((size_t)(rr >> 8) * 16 + h) * 256 + (rr & 255)) * 64 + dd] = f2bf(v);
                    } else {
                        u16* lat = (u16*)C + (size_t)16384 * 1024;
                        lat[(size_t)rr * 128 + (col - 1024)] = f2bf(v);
                    }
                }
            }
        }
    }
}

// ---------------- fused causal attention: builds K,V from latent in-kernel ----------
// r13-verified body + r17 XCD-chunked grid swizzle (bijective, 1024 % 8 == 0).
__global__ __launch_bounds__(256, 2) void attn_fused(const u16* __restrict__ Qh, const u16* __restrict__ Lat,
                                                     const u16* __restrict__ Wu, u16* __restrict__ Y) {
    constexpr int T = 256, HD = 1024;
    constexpr int VS = 264;
    __shared__ __align__(16) u16 lds[33280];     // union: lat[32768] / Ks[16384]+Vt[16896]
    u16* Ks = lds;
    u16* Vt = lds + 16384;

    const int tid = threadIdx.x, lane = tid & 63, wid = tid >> 6;
    const int bh = (blockIdx.x & 7) * 128 + (blockIdx.x >> 3);  // XCD-chunked swizzle
    const int b = bh >> 4, h = bh & 15;
    const size_t base = (size_t)bh * (T * 64);
    const size_t baseY = (size_t)b * T * HD + (size_t)h * 64;

    const int qcol = lane & 31, hi2 = lane >> 5;

    // ---- stage latent (coalesced, chunk-XOR involution within each 16-chunk row) ----
    {
        const u16* latb = Lat + (size_t)b * 256 * 128;
        #pragma unroll
        for (int l = 0; l < 16; l++) {
            int p = l * 256 + tid;
            int c = p ^ ((p >> 4) & 15);
            gload_lds16(latb + (size_t)c * 8, lds + (size_t)(l * 256 + wid * 64) * 8);
        }
    }
    __syncthreads();

    // ---- build K,V tiles in registers from LDS latent + global weights ----
    floatx16 ck[4] = {}, cv[4] = {};   // i = it*2 + dt; tt = wid*2+it
    {
        const u16* wK = Wu + (size_t)(h * 64) * 128;
        const u16* wV = Wu + (size_t)(1024 + h * 64) * 128;
        #pragma unroll
        for (int ks = 0; ks < 8; ks++) {
            short8 kf[2], vf[2];
            #pragma unroll
            for (int dt = 0; dt < 2; dt++) {
                kf[dt] = *(const short8*)&wK[(size_t)(dt * 32 + qcol) * 128 + hi2 * 8 + ks * 16];
                vf[dt] = *(const short8*)&wV[(size_t)(dt * 32 + qcol) * 128 + hi2 * 8 + ks * 16];
            }
            #pragma unroll
            for (int it = 0; it < 2; it++) {
                const int row = (wid * 2 + it) * 32 + qcol;
                const int c = row * 16 + hi2 + 2 * ks;
                short8 lf = *(const short8*)&lds[(size_t)(c ^ (row & 15)) * 8];
                #pragma unroll
                for (int dt = 0; dt < 2; dt++) {
                    ck[it * 2 + dt] = __builtin_amdgcn_mfma_f32_32x32x16_bf16(lf, kf[dt], ck[it * 2 + dt], 0, 0, 0);  // C[t][d]
                    cv[it * 2 + dt] = __builtin_amdgcn_mfma_f32_32x32x16_bf16(vf[dt], lf, cv[it * 2 + dt], 0, 0, 0);  // C[d][t]
                }
            }
        }
    }
    __syncthreads();   // all latent reads retired -> safe to overwrite union

    // ---- write Ks (swizzled) and Vt (padded) ----
    #pragma unroll
    for (int i = 0; i < 4; i++) {
        const int tt = wid * 2 + (i >> 1), dt = i & 1;
        const int dK = dt * 32 + qcol;
        const int tV = tt * 32 + qcol;
        #pragma unroll
        for (int r = 0; r < 16; r++) {
            const int rloc = (r & 3) + 8 * (r >> 2) + 4 * hi2;
            const int t = tt * 32 + rloc;
            const int xt = (t & 7) ^ ((t >> 3) & 3);
            Ks[t * 64 + (((dK >> 3) ^ xt) << 3) + (dK & 7)] = f2bf(ck[i][r]);
            Vt[(dt * 32 + rloc) * VS + tV] = f2bf(cv[i][r]);
        }
    }
    __syncthreads();

    const float c_exp = 0.125f * 1.44269504088896f;
    const u16* qbase = Qh + base;
    const u16* vrow0 = &Vt[qcol * VS];
    const u16* vrow1 = &Vt[(qcol + 32) * VS];

    #pragma unroll 1
    for (int half = 0; half < 2; half++) {
        const int qb = half ? (7 - wid) : wid;

        short8 qf[4];
        {
            const u16* qp = &qbase[(size_t)(qb * 32 + qcol) * 64 + hi2 * 8];
            #pragma unroll
            for (int i = 0; i < 4; i++) qf[i] = *(const short8*)&qp[i * 16];
        }

        floatx16 y0 = {0}, y1 = {0};
        float lsum = 0.f;

        for (int kt = 0; kt <= qb; kt++) {
            const int tK = kt * 32 + qcol;
            const int xt = (tK & 7) ^ ((tK >> 3) & 3);
            const u16* kp = &Ks[tK * 64];
            floatx16 s = {0};
            #pragma unroll
            for (int i = 0; i < 4; i++) {
                short8 kf = *(const short8*)&kp[((i * 2 + hi2) ^ xt) << 3];
                s = __builtin_amdgcn_mfma_f32_32x32x16_bf16(kf, qf[i], s, 0, 0, 0);
            }

            const bool diag = (kt == qb);
            u32 pk[8];
            #pragma unroll
            for (int r2 = 0; r2 < 8; r2++) {
                const int r0 = 2 * r2;
                const int kr0 = (r0 & 3) + 8 * (r0 >> 2) + 4 * hi2;
                float p0 = exp2f(s[r0] * c_exp);
                float p1 = exp2f(s[r0 + 1] * c_exp);
                if (diag) {
                    if (kr0 > qcol) p0 = 0.f;
                    if (kr0 + 1 > qcol) p1 = 0.f;
                }
                lsum += p0 + p1;
                pk[r2] = (u32)f2bf(p0) | ((u32)f2bf(p1) << 16);
            }

            #pragma unroll
            for (int kh2 = 0; kh2 < 2; kh2++) {
                u32 a0 = pk[kh2 * 4 + 0], a1 = pk[kh2 * 4 + 1];
                u32 b0 = pk[kh2 * 4 + 2], b1 = pk[kh2 * 4 + 3];
                asm volatile("v_permlane32_swap_b32 %0, %1" : "+v"(a0), "+v"(b0));
                asm volatile("v_permlane32_swap_b32 %0, %1" : "+v"(a1), "+v"(b1));
                int4 w;
                w.x = (int)a0; w.y = (int)a1; w.z = (int)b0; w.w = (int)b1;
                short8 pa = __builtin_bit_cast(short8, w);
                const int tofs = kt * 32 + kh2 * 16 + hi2 * 8;
                short8 vf0 = *(const short8*)&vrow0[tofs];
                short8 vf1 = *(const short8*)&vrow1[tofs];
                y0 = __builtin_amdgcn_mfma_f32_32x32x16_bf16(pa, vf0, y0, 0, 0, 0);
                y1 = __builtin_amdgcn_mfma_f32_32x32x16_bf16(pa, vf1, y1, 0, 0, 0);
            }
        }

        lsum += __shfl_xor(lsum, 32);
        const float linv = 1.0f / lsum;

        float sc[16];
        #pragma unroll
        for (int r = 0; r < 16; r++)
            sc[r] = __shfl(linv, (r & 3) + 8 * (r >> 2) + 4 * hi2, 64);

        #pragma unroll
        for (int r = 0; r < 16; r++) {
            const int qloc = (r & 3) + 8 * (r >> 2) + 4 * hi2;
            const size_t rowoff = baseY + (size_t)(qb * 32 + qloc) * HD;
            Y[rowoff + qcol]      = f2bf(y0[r] * sc[r]);
            Y[rowoff + 32 + qcol] = f2bf(y1[r] * sc[r]);
        }
    }
}

extern "C" void kernel_launch(void* const* d_in, const int* in_sizes, int n_in,
                              void* d_out, int out_size, void* d_ws, size_t ws_size,
                              hipStream_t stream) {
    const float* x         = (const float*)d_in[0];
    const float* w_kv_down = (const float*)d_in[1];
    const float* w_kv_up   = (const float*)d_in[2];
    const float* w_q       = (const float*)d_in[3];
    const float* w_out     = (const float*)d_in[4];
    float* out = (float*)d_out;

    constexpr int Bb = 64, Tt = 256, Cc = 1024, HD = 1024, R = 128;
    constexpr int M = Bb * Tt;  // 16384

    char* ws = (char*)d_ws;
    auto alloc = [&](size_t bytes) {
        void* p = (void*)ws;
        ws += (bytes + 255) & ~(size_t)255;
        return p;
    };
    u16* wql_t   = (u16*)alloc((size_t)(HD + R) * Cc * 2);  // rows 0..1023 Wq^T, 1024..1151 Wkvd^T
    u16* wkvu_t  = (u16*)alloc((size_t)2 * HD * R * 2);
    u16* wo_t    = (u16*)alloc((size_t)Cc * HD * 2);
    u16* qh      = (u16*)alloc((size_t)M * HD * 2);      // per-head packed q  [b][h][t][64]
    u16* latentb = (u16*)alloc((size_t)M * R * 2);       // adjacent to qh (MODE 4 epilogue)
    u16* yb      = (u16*)alloc((size_t)M * HD * 2);

    // prep: weight transposes only (x-cvt fused into gemm4's staging)
    prep<<<2432, 256, 0, stream>>>(w_q, w_kv_down, w_kv_up, w_out, wql_t, wkvu_t, wo_t);

    // q + latent fused, A = raw f32 x (convert-on-stage): N=1152, grid 128*9
    gemm_bt64<4><<<dim3(128 * 9), 256, 0, stream>>>(x, wql_t, qh, M, HD + R, Cc, 9);
    // fused attention (builds K,V from latent in-kernel; XCD-chunked grid)
    attn_fused<<<Bb * 16, 256, 0, stream>>>(qh, latentb, wkvu_t, yb);
    // out = y @ Wout (M x 1024 x 1024), fp32; grid 128*8 = 1024
    gemm_bt64<0><<<dim3(128 * 8), 256, 0, stream>>>(yb, wo_t, out, M, Cc, HD, 8);
}

// Round 19
// 151.120 us; speedup vs baseline: 1.3872x; 1.3872x over previous
//
#include <hip/hip_runtime.h>
#include <hip/hip_bf16.h>
#include <cstdint>
#include <cstddef>

typedef short short8 __attribute__((ext_vector_type(8)));
typedef float floatx4 __attribute__((ext_vector_type(4)));
typedef float floatx16 __attribute__((ext_vector_type(16)));
typedef unsigned short u16;
typedef unsigned int u32;

__device__ __forceinline__ u16 f2bf(float f) {
    __hip_bfloat16 h = __float2bfloat16(f);
    return __builtin_bit_cast(u16, h);
}

__device__ __forceinline__ void gload_lds16(const void* g, void* l) {
    __builtin_amdgcn_global_load_lds(
        (const __attribute__((address_space(1))) void*)g,
        (__attribute__((address_space(3))) void*)l, 16, 0, 0);
}

// ---------------- fused prep: x f32->bf16 + all weight transposes ----------------
// (r17-proven; r18's cvt-fusion into gemm4 staging REGRESSED 3.5x — reg-staged A
// serializes load->wait->ds_write inside the 2-phase barriers, MfmaUtil 29->8%.)
__global__ __launch_bounds__(256) void prep(const float* __restrict__ x, u16* __restrict__ xb,
                                            const float* __restrict__ wq, const float* __restrict__ wkvd,
                                            const float* __restrict__ wkvu, const float* __restrict__ wo,
                                            u16* __restrict__ wql_t, u16* __restrict__ wkvu_t,
                                            u16* __restrict__ wo_t) {
    const int b = blockIdx.x;
    if (b < 2048) {
        const int n4 = 16384 * 1024 / 4;
        for (int i = b * 256 + threadIdx.x; i < n4; i += 2048 * 256) {
            float4 v = ((const float4*)x)[i];
            ushort4 o;
            o.x = f2bf(v.x); o.y = f2bf(v.y); o.z = f2bf(v.z); o.w = f2bf(v.w);
            ((ushort4*)xb)[i] = o;
        }
    } else {
        __shared__ float tile[32][33];
        const float* W; u16* Wt; int K, N, lb;
        if (b < 3072)      { W = wq;   Wt = wql_t;                       K = 1024; N = 1024; lb = b - 2048; }
        else if (b < 3200) { W = wkvd; Wt = wql_t + (size_t)1024 * 1024; K = 1024; N = 128;  lb = b - 3072; }
        else if (b < 3456) { W = wkvu; Wt = wkvu_t;                      K = 128;  N = 2048; lb = b - 3200; }
        else               { W = wo;   Wt = wo_t;                        K = 1024; N = 1024; lb = b - 3456; }
        const int nb = N / 32;
        const int n0 = (lb % nb) * 32, k0 = (lb / nb) * 32;
        const int tx = threadIdx.x & 31, ty = threadIdx.x >> 5;
        #pragma unroll
        for (int i = 0; i < 32; i += 8)
            tile[ty + i][tx] = W[(size_t)(k0 + ty + i) * N + n0 + tx];
        __syncthreads();
        #pragma unroll
        for (int i = 0; i < 32; i += 8)
            Wt[(size_t)(n0 + ty + i) * K + k0 + tx] = f2bf(tile[tx][ty + i]);
    }
}

// ---------------- 128x128 BK=64 bf16 GEMM: C = A[M][K] * Bt[N][K]^T ----------------
// r13-proven configuration (gemm 52/52 us, MfmaUtil ~30%, 0 bank conflicts, VGPR 64):
// 16x16x32 MFMA, 2-phase m97-class, 256 threads / 4 waves (2x2), wave tile 64x64,
// single 32KB LDS/operand, chunk-XOR involution, launch_bounds(256,4).
// DO NOT RE-TRY (measured regressions): 32x32x16 frags (4.7M conflicts, r14);
// launch_bounds(256,5) (VGPR cap 48 -> acc spill, FETCH 4.5x, r15);
// reg-staged A with in-loop f32 cvt (serial latency chain, MfmaUtil 8%, r18).
template <int MODE>
__global__ __launch_bounds__(256, 4) void gemm_bt64(const u16* __restrict__ A, const u16* __restrict__ Bt,
                                                    void* __restrict__ C, int M, int N, int K, int ncols) {
    __shared__ __align__(16) u16 As[128 * 64];
    __shared__ __align__(16) u16 Bs[128 * 64];
    const int tid = threadIdx.x;
    const int lane = tid & 63, wid = tid >> 6;
    const int wr = wid >> 1, wc = wid & 1;
    const int l15 = lane & 15, hi = lane >> 4;

    const int nwg = gridDim.x, q8 = nwg >> 3;
    const int wg = (blockIdx.x & 7) * q8 + (blockIdx.x >> 3);
    const int m0 = (wg / ncols) * 128, n0 = (wg % ncols) * 128;

    const u16* Ab = A + (size_t)m0 * K;
    const u16* Bb = Bt + (size_t)n0 * K;

    u32 soff[4];
    #pragma unroll
    for (int l = 0; l < 4; l++) {
        int p = l * 256 + tid, c = p ^ ((p >> 3) & 7);
        soff[l] = (u32)((c >> 3) * K + (c & 7) * 8);
    }

    int afo[4][2], bfo[4][2];
    #pragma unroll
    for (int i = 0; i < 4; i++) {
        #pragma unroll
        for (int ks = 0; ks < 2; ks++) {
            int ra = wr * 64 + i * 16 + l15;
            afo[i][ks] = ((ra * 8 + ks * 4 + hi) ^ (ra & 7)) * 8;
            int rb = wc * 64 + i * 16 + l15;
            bfo[i][ks] = ((rb * 8 + ks * 4 + hi) ^ (rb & 7)) * 8;
        }
    }

    floatx4 acc[4][4] = {};

    for (int k0 = 0; k0 < K; k0 += 64) {
        #pragma unroll
        for (int l = 0; l < 4; l++)
            gload_lds16(Ab + soff[l] + k0, As + (size_t)(l * 256 + wid * 64) * 8);
        #pragma unroll
        for (int l = 0; l < 4; l++)
            gload_lds16(Bb + soff[l] + k0, Bs + (size_t)(l * 256 + wid * 64) * 8);
        __syncthreads();
        #pragma unroll
        for (int ks = 0; ks < 2; ks++) {
            short8 af[4], bf[4];
            #pragma unroll
            for (int i = 0; i < 4; i++) af[i] = *(const short8*)&As[afo[i][ks]];
            #pragma unroll
            for (int j = 0; j < 4; j++) bf[j] = *(const short8*)&Bs[bfo[j][ks]];
            #pragma unroll
            for (int i = 0; i < 4; i++) {
                #pragma unroll
                for (int j = 0; j < 4; j++)
                    acc[i][j] = __builtin_amdgcn_mfma_f32_16x16x32_bf16(af[i], bf[j], acc[i][j], 0, 0, 0);
            }
        }
        __syncthreads();
    }

    const int cr = hi * 4, cc = l15;
    #pragma unroll
    for (int i = 0; i < 4; i++) {
        #pragma unroll
        for (int j = 0; j < 4; j++) {
            int row = m0 + wr * 64 + i * 16 + cr;
            int col = n0 + wc * 64 + j * 16 + cc;
            #pragma unroll
            for (int r = 0; r < 4; r++) {
                float v = acc[i][j][r];
                int rr = row + r;
                if (MODE == 0) {
                    ((float*)C)[(size_t)rr * N + col] = v;
                } else {  // MODE 4
                    if (col < 1024) {
                        int h = col >> 6, dd = col & 63;
                        ((u16*)C)[(((size_t)(rr >> 8) * 16 + h) * 256 + (rr & 255)) * 64 + dd] = f2bf(v);
                    } else {
                        u16* lat = (u16*)C + (size_t)16384 * 1024;
                        lat[(size_t)rr * 128 + (col - 1024)] = f2bf(v);
                    }
                }
            }
        }
    }
}

// ---------------- fused causal attention: builds K,V from latent in-kernel ----------
// r13-verified body + r17 XCD-chunked grid swizzle (bijective, 1024 % 8 == 0).
__global__ __launch_bounds__(256, 2) void attn_fused(const u16* __restrict__ Qh, const u16* __restrict__ Lat,
                                                     const u16* __restrict__ Wu, u16* __restrict__ Y) {
    constexpr int T = 256, HD = 1024;
    constexpr int VS = 264;
    __shared__ __align__(16) u16 lds[33280];     // union: lat[32768] / Ks[16384]+Vt[16896]
    u16* Ks = lds;
    u16* Vt = lds + 16384;

    const int tid = threadIdx.x, lane = tid & 63, wid = tid >> 6;
    const int bh = (blockIdx.x & 7) * 128 + (blockIdx.x >> 3);  // XCD-chunked swizzle
    const int b = bh >> 4, h = bh & 15;
    const size_t base = (size_t)bh * (T * 64);
    const size_t baseY = (size_t)b * T * HD + (size_t)h * 64;

    const int qcol = lane & 31, hi2 = lane >> 5;

    // ---- stage latent (coalesced, chunk-XOR involution within each 16-chunk row) ----
    {
        const u16* latb = Lat + (size_t)b * 256 * 128;
        #pragma unroll
        for (int l = 0; l < 16; l++) {
            int p = l * 256 + tid;
            int c = p ^ ((p >> 4) & 15);
            gload_lds16(latb + (size_t)c * 8, lds + (size_t)(l * 256 + wid * 64) * 8);
        }
    }
    __syncthreads();

    // ---- build K,V tiles in registers from LDS latent + global weights ----
    floatx16 ck[4] = {}, cv[4] = {};   // i = it*2 + dt; tt = wid*2+it
    {
        const u16* wK = Wu + (size_t)(h * 64) * 128;
        const u16* wV = Wu + (size_t)(1024 + h * 64) * 128;
        #pragma unroll
        for (int ks = 0; ks < 8; ks++) {
            short8 kf[2], vf[2];
            #pragma unroll
            for (int dt = 0; dt < 2; dt++) {
                kf[dt] = *(const short8*)&wK[(size_t)(dt * 32 + qcol) * 128 + hi2 * 8 + ks * 16];
                vf[dt] = *(const short8*)&wV[(size_t)(dt * 32 + qcol) * 128 + hi2 * 8 + ks * 16];
            }
            #pragma unroll
            for (int it = 0; it < 2; it++) {
                const int row = (wid * 2 + it) * 32 + qcol;
                const int c = row * 16 + hi2 + 2 * ks;
                short8 lf = *(const short8*)&lds[(size_t)(c ^ (row & 15)) * 8];
                #pragma unroll
                for (int dt = 0; dt < 2; dt++) {
                    ck[it * 2 + dt] = __builtin_amdgcn_mfma_f32_32x32x16_bf16(lf, kf[dt], ck[it * 2 + dt], 0, 0, 0);  // C[t][d]
                    cv[it * 2 + dt] = __builtin_amdgcn_mfma_f32_32x32x16_bf16(vf[dt], lf, cv[it * 2 + dt], 0, 0, 0);  // C[d][t]
                }
            }
        }
    }
    __syncthreads();   // all latent reads retired -> safe to overwrite union

    // ---- write Ks (swizzled) and Vt (padded) ----
    #pragma unroll
    for (int i = 0; i < 4; i++) {
        const int tt = wid * 2 + (i >> 1), dt = i & 1;
        const int dK = dt * 32 + qcol;
        const int tV = tt * 32 + qcol;
        #pragma unroll
        for (int r = 0; r < 16; r++) {
            const int rloc = (r & 3) + 8 * (r >> 2) + 4 * hi2;
            const int t = tt * 32 + rloc;
            const int xt = (t & 7) ^ ((t >> 3) & 3);
            Ks[t * 64 + (((dK >> 3) ^ xt) << 3) + (dK & 7)] = f2bf(ck[i][r]);
            Vt[(dt * 32 + rloc) * VS + tV] = f2bf(cv[i][r]);
        }
    }
    __syncthreads();

    const float c_exp = 0.125f * 1.44269504088896f;
    const u16* qbase = Qh + base;
    const u16* vrow0 = &Vt[qcol * VS];
    const u16* vrow1 = &Vt[(qcol + 32) * VS];

    #pragma unroll 1
    for (int half = 0; half < 2; half++) {
        const int qb = half ? (7 - wid) : wid;

        short8 qf[4];
        {
            const u16* qp = &qbase[(size_t)(qb * 32 + qcol) * 64 + hi2 * 8];
            #pragma unroll
            for (int i = 0; i < 4; i++) qf[i] = *(const short8*)&qp[i * 16];
        }

        floatx16 y0 = {0}, y1 = {0};
        float lsum = 0.f;

        for (int kt = 0; kt <= qb; kt++) {
            const int tK = kt * 32 + qcol;
            const int xt = (tK & 7) ^ ((tK >> 3) & 3);
            const u16* kp = &Ks[tK * 64];
            floatx16 s = {0};
            #pragma unroll
            for (int i = 0; i < 4; i++) {
                short8 kf = *(const short8*)&kp[((i * 2 + hi2) ^ xt) << 3];
                s = __builtin_amdgcn_mfma_f32_32x32x16_bf16(kf, qf[i], s, 0, 0, 0);
            }

            const bool diag = (kt == qb);
            u32 pk[8];
            #pragma unroll
            for (int r2 = 0; r2 < 8; r2++) {
                const int r0 = 2 * r2;
                const int kr0 = (r0 & 3) + 8 * (r0 >> 2) + 4 * hi2;
                float p0 = exp2f(s[r0] * c_exp);
                float p1 = exp2f(s[r0 + 1] * c_exp);
                if (diag) {
                    if (kr0 > qcol) p0 = 0.f;
                    if (kr0 + 1 > qcol) p1 = 0.f;
                }
                lsum += p0 + p1;
                pk[r2] = (u32)f2bf(p0) | ((u32)f2bf(p1) << 16);
            }

            #pragma unroll
            for (int kh2 = 0; kh2 < 2; kh2++) {
                u32 a0 = pk[kh2 * 4 + 0], a1 = pk[kh2 * 4 + 1];
                u32 b0 = pk[kh2 * 4 + 2], b1 = pk[kh2 * 4 + 3];
                asm volatile("v_permlane32_swap_b32 %0, %1" : "+v"(a0), "+v"(b0));
                asm volatile("v_permlane32_swap_b32 %0, %1" : "+v"(a1), "+v"(b1));
                int4 w;
                w.x = (int)a0; w.y = (int)a1; w.z = (int)b0; w.w = (int)b1;
                short8 pa = __builtin_bit_cast(short8, w);
                const int tofs = kt * 32 + kh2 * 16 + hi2 * 8;
                short8 vf0 = *(const short8*)&vrow0[tofs];
                short8 vf1 = *(const short8*)&vrow1[tofs];
                y0 = __builtin_amdgcn_mfma_f32_32x32x16_bf16(pa, vf0, y0, 0, 0, 0);
                y1 = __builtin_amdgcn_mfma_f32_32x32x16_bf16(pa, vf1, y1, 0, 0, 0);
            }
        }

        lsum += __shfl_xor(lsum, 32);
        const float linv = 1.0f / lsum;

        float sc[16];
        #pragma unroll
        for (int r = 0; r < 16; r++)
            sc[r] = __shfl(linv, (r & 3) + 8 * (r >> 2) + 4 * hi2, 64);

        #pragma unroll
        for (int r = 0; r < 16; r++) {
            const int qloc = (r & 3) + 8 * (r >> 2) + 4 * hi2;
            const size_t rowoff = baseY + (size_t)(qb * 32 + qloc) * HD;
            Y[rowoff + qcol]      = f2bf(y0[r] * sc[r]);
            Y[rowoff + 32 + qcol] = f2bf(y1[r] * sc[r]);
        }
    }
}

extern "C" void kernel_launch(void* const* d_in, const int* in_sizes, int n_in,
                              void* d_out, int out_size, void* d_ws, size_t ws_size,
                              hipStream_t stream) {
    const float* x         = (const float*)d_in[0];
    const float* w_kv_down = (const float*)d_in[1];
    const float* w_kv_up   = (const float*)d_in[2];
    const float* w_q       = (const float*)d_in[3];
    const float* w_out     = (const float*)d_in[4];
    float* out = (float*)d_out;

    constexpr int Bb = 64, Tt = 256, Cc = 1024, HD = 1024, R = 128;
    constexpr int M = Bb * Tt;  // 16384

    char* ws = (char*)d_ws;
    auto alloc = [&](size_t bytes) {
        void* p = (void*)ws;
        ws += (bytes + 255) & ~(size_t)255;
        return p;
    };
    u16* xb      = (u16*)alloc((size_t)M * Cc * 2);
    u16* wql_t   = (u16*)alloc((size_t)(HD + R) * Cc * 2);  // rows 0..1023 Wq^T, 1024..1151 Wkvd^T
    u16* wkvu_t  = (u16*)alloc((size_t)2 * HD * R * 2);
    u16* wo_t    = (u16*)alloc((size_t)Cc * HD * 2);
    u16* qh      = (u16*)alloc((size_t)M * HD * 2);      // per-head packed q  [b][h][t][64]
    u16* latentb = (u16*)alloc((size_t)M * R * 2);       // adjacent to qh (MODE 4 epilogue)
    u16* yb      = (u16*)alloc((size_t)M * HD * 2);

    // fused prep: cvt + all weight transposes (one launch)
    prep<<<4480, 256, 0, stream>>>(x, xb, w_q, w_kv_down, w_kv_up, w_out, wql_t, wkvu_t, wo_t);

    // q + latent fused: N=1152 exactly, grid 128*9 = 1152 (div by 8)
    gemm_bt64<4><<<dim3(128 * 9), 256, 0, stream>>>(xb, wql_t, qh, M, HD + R, Cc, 9);
    // fused attention (builds K,V from latent in-kernel; XCD-chunked grid)
    attn_fused<<<Bb * 16, 256, 0, stream>>>(qh, latentb, wkvu_t, yb);
    // out = y @ Wout (M x 1024 x 1024), fp32; grid 128*8 = 1024
    gemm_bt64<0><<<dim3(128 * 8), 256, 0, stream>>>(yb, wo_t, out, M, Cc, HD, 8);
}